// Round 4
// baseline (63.612 us; speedup 1.0000x reference)
//
#include <hip/hip_runtime.h>

#define DIM 4096
#define LN_EPS 1e-5f
#define NTHREADS 512
#define VPT 2   // 2 float4 = 8 floats/thread; 512*8 = 4096 = DIM
#define NWAVES (NTHREADS / 64)

typedef float vfloat4 __attribute__((ext_vector_type(4)));

__global__ __launch_bounds__(NTHREADS) void crosslayer_ln_kernel(
    const float* __restrict__ x,
    const float* __restrict__ x0,
    const float* __restrict__ w,
    const float* __restrict__ bias,
    const float* __restrict__ gamma,
    const float* __restrict__ beta,
    float* __restrict__ out)
{
    const int row = blockIdx.x;
    const int tid = threadIdx.x;
    const int wave = tid >> 6;
    const int lane = tid & 63;

    const float4* __restrict__ x0v = reinterpret_cast<const float4*>(x0 + (size_t)row * DIM);
    const float4* __restrict__ xv  = reinterpret_cast<const float4*>(x  + (size_t)row * DIM);
    const float4* __restrict__ wv  = reinterpret_cast<const float4*>(w);
    const float4* __restrict__ bv  = reinterpret_cast<const float4*>(bias);
    const float4* __restrict__ gv  = reinterpret_cast<const float4*>(gamma);
    const float4* __restrict__ btv = reinterpret_cast<const float4*>(beta);
    vfloat4* __restrict__ ov = reinterpret_cast<vfloat4*>(out + (size_t)row * DIM);

    const int i0 = tid;
    const int i1 = NTHREADS + tid;

    // ---- Single fused pass: issue all loads, compute 6 partial sums ----
    const float4 a0 = x0v[i0];
    const float4 a1 = x0v[i1];
    const float4 w0 = wv[i0];
    const float4 w1 = wv[i1];
    const float4 xA = xv[i0];
    const float4 xB = xv[i1];
    const float4 bA = bv[i0];
    const float4 bB = bv[i1];

    float dot = a0.x*w0.x + a0.y*w0.y + a0.z*w0.z + a0.w*w0.w
              + a1.x*w1.x + a1.y*w1.y + a1.z*w1.z + a1.w*w1.w;
    float Sx  = xA.x + xA.y + xA.z + xA.w + xB.x + xB.y + xB.z + xB.w;
    float Sxx = xA.x*xA.x + xA.y*xA.y + xA.z*xA.z + xA.w*xA.w
              + xB.x*xB.x + xB.y*xB.y + xB.z*xB.z + xB.w*xB.w;
    float Sxb = xA.x*bA.x + xA.y*bA.y + xA.z*bA.z + xA.w*bA.w
              + xB.x*bB.x + xB.y*bB.y + xB.z*bB.z + xB.w*bB.w;
    float Sb  = bA.x + bA.y + bA.z + bA.w + bB.x + bB.y + bB.z + bB.w;
    float Sbb = bA.x*bA.x + bA.y*bA.y + bA.z*bA.z + bA.w*bA.w
              + bB.x*bB.x + bB.y*bB.y + bB.z*bB.z + bB.w*bB.w;

    // issue gamma/beta loads now; latency hides under the reduction
    const float4 gA  = gv[i0];
    const float4 gB  = gv[i1];
    const float4 btA = btv[i0];
    const float4 btB = btv[i1];

    // wave64 butterfly reduce of 6 values
    #pragma unroll
    for (int o = 1; o < 64; o <<= 1) {
        dot += __shfl_xor(dot, o, 64);
        Sx  += __shfl_xor(Sx,  o, 64);
        Sxx += __shfl_xor(Sxx, o, 64);
        Sxb += __shfl_xor(Sxb, o, 64);
        Sb  += __shfl_xor(Sb,  o, 64);
        Sbb += __shfl_xor(Sbb, o, 64);
    }

    __shared__ float red[6][NWAVES];
    if (lane == 0) {
        red[0][wave] = dot; red[1][wave] = Sx;  red[2][wave] = Sxx;
        red[3][wave] = Sxb; red[4][wave] = Sb;  red[5][wave] = Sbb;
    }
    __syncthreads();

    float tdot = 0.f, tSx = 0.f, tSxx = 0.f, tSxb = 0.f, tSb = 0.f, tSbb = 0.f;
    #pragma unroll
    for (int i = 0; i < NWAVES; ++i) {
        tdot += red[0][i]; tSx  += red[1][i]; tSxx += red[2][i];
        tSxb += red[3][i]; tSb  += red[4][i]; tSbb += red[5][i];
    }

    const float m    = 1.f + tdot;                       // pre = m*x + bias
    const float mean = (m * tSx + tSb) * (1.f / DIM);
    const float Ex2  = (m * m * tSxx + 2.f * m * tSxb + tSbb) * (1.f / DIM);
    const float var  = Ex2 - mean * mean;
    const float inv  = rsqrtf(var + LN_EPS);

    // ---- Output pass: pre recomputed from registers, nt store ----
    vfloat4 o0, o1;
    o0.x = fmaf((fmaf(m, xA.x, bA.x) - mean) * inv, gA.x, btA.x);
    o0.y = fmaf((fmaf(m, xA.y, bA.y) - mean) * inv, gA.y, btA.y);
    o0.z = fmaf((fmaf(m, xA.z, bA.z) - mean) * inv, gA.z, btA.z);
    o0.w = fmaf((fmaf(m, xA.w, bA.w) - mean) * inv, gA.w, btA.w);
    o1.x = fmaf((fmaf(m, xB.x, bB.x) - mean) * inv, gB.x, btB.x);
    o1.y = fmaf((fmaf(m, xB.y, bB.y) - mean) * inv, gB.y, btB.y);
    o1.z = fmaf((fmaf(m, xB.z, bB.z) - mean) * inv, gB.z, btB.z);
    o1.w = fmaf((fmaf(m, xB.w, bB.w) - mean) * inv, gB.w, btB.w);
    __builtin_nontemporal_store(o0, &ov[i0]);
    __builtin_nontemporal_store(o1, &ov[i1]);
}

extern "C" void kernel_launch(void* const* d_in, const int* in_sizes, int n_in,
                              void* d_out, int out_size, void* d_ws, size_t ws_size,
                              hipStream_t stream) {
    const float* x     = (const float*)d_in[0];
    const float* x0    = (const float*)d_in[1];
    const float* w     = (const float*)d_in[2];
    const float* bias  = (const float*)d_in[3];
    const float* gamma = (const float*)d_in[4];
    const float* beta  = (const float*)d_in[5];
    float* out = (float*)d_out;

    const int B = in_sizes[0] / DIM;   // 8192
    crosslayer_ln_kernel<<<B, NTHREADS, 0, stream>>>(x, x0, w, bias, gamma, beta, out);
}